// Round 4
// baseline (66.466 us; speedup 1.0000x reference)
//
#include <hip/hip_runtime.h>
#include <math.h>

#define B 512
#define DG 1024
#define P 1024
#define DA 256
#define LDP 68   // padded leading dim for [32][LDP] stage tiles (272B rows, 16B-aligned)

// ---------------------------------------------------------------- utilities
__device__ __forceinline__ float block_reduce_sum(float v, volatile float* red) {
    #pragma unroll
    for (int off = 32; off > 0; off >>= 1) v += __shfl_down(v, off, 64);
    const int lane = threadIdx.x & 63, wid = threadIdx.x >> 6;
    __syncthreads();
    if (lane == 0) red[wid] = v;
    __syncthreads();
    return red[0] + red[1] + red[2] + red[3];
}

#define FMA16(a4, b4, acc)                                   \
    acc[0][0] = fmaf(a4.x, b4.x, acc[0][0]);                 \
    acc[0][1] = fmaf(a4.x, b4.y, acc[0][1]);                 \
    acc[0][2] = fmaf(a4.x, b4.z, acc[0][2]);                 \
    acc[0][3] = fmaf(a4.x, b4.w, acc[0][3]);                 \
    acc[1][0] = fmaf(a4.y, b4.x, acc[1][0]);                 \
    acc[1][1] = fmaf(a4.y, b4.y, acc[1][1]);                 \
    acc[1][2] = fmaf(a4.y, b4.z, acc[1][2]);                 \
    acc[1][3] = fmaf(a4.y, b4.w, acc[1][3]);                 \
    acc[2][0] = fmaf(a4.z, b4.x, acc[2][0]);                 \
    acc[2][1] = fmaf(a4.z, b4.y, acc[2][1]);                 \
    acc[2][2] = fmaf(a4.z, b4.z, acc[2][2]);                 \
    acc[2][3] = fmaf(a4.z, b4.w, acc[2][3]);                 \
    acc[3][0] = fmaf(a4.w, b4.x, acc[3][0]);                 \
    acc[3][1] = fmaf(a4.w, b4.y, acc[3][1]);                 \
    acc[3][2] = fmaf(a4.w, b4.z, acc[3][2]);                 \
    acc[3][3] = fmaf(a4.w, b4.w, acc[3][3]);

#define FMA8(a0, a1, b4, acc)                                \
    acc[0][0] = fmaf(a0, b4.x, acc[0][0]);                   \
    acc[0][1] = fmaf(a0, b4.y, acc[0][1]);                   \
    acc[0][2] = fmaf(a0, b4.z, acc[0][2]);                   \
    acc[0][3] = fmaf(a0, b4.w, acc[0][3]);                   \
    acc[1][0] = fmaf(a1, b4.x, acc[1][0]);                   \
    acc[1][1] = fmaf(a1, b4.y, acc[1][1]);                   \
    acc[1][2] = fmaf(a1, b4.z, acc[1][2]);                   \
    acc[1][3] = fmaf(a1, b4.w, acc[1][3]);

// ---------------------------------------------------------------- KA mega-kernel (all inputs independent):
//  bi in [0,256)    : k1  - qp[ks] partial of hg(512x1024)@Wq^T, 64x64 tile, 4x4 acc, KS=8
//  bi in [256,384)  : G   - G[e][p] = sum_d Vk[e,d]*gk[d]*Ek[p,d], 32x64 tiles
//  bi == 384        : vec4- chained matvecs: vec4[j] = Uq^T @ (Vk @ w4[j])
//  bi in [385,1409) : kp  - per-p LN stats for k and v
__global__ __launch_bounds__(256) void KA(const float* __restrict__ hg, const float* __restrict__ Wq,
                                          const float* __restrict__ Uq, const float* __restrict__ Vk,
                                          const float* __restrict__ Ek, const float* __restrict__ Ev,
                                          const float* __restrict__ wk, const float* __restrict__ bk,
                                          const float* __restrict__ wv, const float* __restrict__ bv,
                                          const float* __restrict__ gk, const float* __restrict__ bkln,
                                          float* __restrict__ qp, float* __restrict__ Gm,
                                          float* __restrict__ pst, float* __restrict__ scal4,
                                          float* __restrict__ vec4) {
    __shared__ __align__(16) float sA[32 * LDP];
    __shared__ __align__(16) float sB[32 * LDP];
    __shared__ float red[4];
    const int tid = threadIdx.x;
    const int bi = blockIdx.x;

    if (bi < 256) {
        // ---- k1: 64x64 tile, KS=8 (K-chunk 128)
        const int mt = bi & 7, nt = (bi >> 3) & 3, ks = bi >> 5;
        const int b0 = mt * 64, d0 = nt * 64, kc = ks * 128;
        const int sm = tid >> 3, sk4 = (tid & 7) * 4;
        const int ty4 = (tid >> 4) * 4, tx4 = (tid & 15) * 4;
        float acc[4][4] = {};
        for (int kt = 0; kt < 128; kt += 32) {
            const int kg = kc + kt;
            #pragma unroll
            for (int pass = 0; pass < 2; ++pass) {
                int m = sm + pass * 32;
                float4 av = *reinterpret_cast<const float4*>(&hg[(b0 + m) * DG + kg + sk4]);
                sA[(sk4 + 0) * LDP + m] = av.x; sA[(sk4 + 1) * LDP + m] = av.y;
                sA[(sk4 + 2) * LDP + m] = av.z; sA[(sk4 + 3) * LDP + m] = av.w;
                float4 wv4 = *reinterpret_cast<const float4*>(&Wq[(d0 + m) * DG + kg + sk4]);
                sB[(sk4 + 0) * LDP + m] = wv4.x; sB[(sk4 + 1) * LDP + m] = wv4.y;
                sB[(sk4 + 2) * LDP + m] = wv4.z; sB[(sk4 + 3) * LDP + m] = wv4.w;
            }
            __syncthreads();
            #pragma unroll
            for (int kk = 0; kk < 32; ++kk) {
                float4 a4 = *reinterpret_cast<const float4*>(&sA[kk * LDP + ty4]);
                float4 b4 = *reinterpret_cast<const float4*>(&sB[kk * LDP + tx4]);
                FMA16(a4, b4, acc)
            }
            __syncthreads();
        }
        float* outp = qp + ks * (B * DA);
        #pragma unroll
        for (int i = 0; i < 4; ++i) {
            float4 o = make_float4(acc[i][0], acc[i][1], acc[i][2], acc[i][3]);
            *reinterpret_cast<float4*>(&outp[(b0 + ty4 + i) * DA + d0 + tx4]) = o;
        }
    } else if (bi < 384) {
        // ---- G: 32(e) x 64(p) tile, K=d=256; A=Vk*gk transposed, B=Ek transposed
        const int b2 = bi - 256;
        const int e0 = (b2 & 7) * 32, p0 = (b2 >> 3) * 64;
        const int sm = tid >> 3, sk4 = (tid & 7) * 4;
        const int ty = tid >> 4, tx4 = (tid & 15) * 4;
        float acc[2][4] = {};
        for (int kt = 0; kt < 256; kt += 32) {
            float4 vv = *reinterpret_cast<const float4*>(&Vk[(e0 + sm) * DA + kt + sk4]);
            float4 gg = *reinterpret_cast<const float4*>(&gk[kt + sk4]);
            sA[(sk4 + 0) * LDP + sm] = vv.x * gg.x; sA[(sk4 + 1) * LDP + sm] = vv.y * gg.y;
            sA[(sk4 + 2) * LDP + sm] = vv.z * gg.z; sA[(sk4 + 3) * LDP + sm] = vv.w * gg.w;
            #pragma unroll
            for (int pass = 0; pass < 2; ++pass) {
                int m = sm + pass * 32;
                float4 ee = *reinterpret_cast<const float4*>(&Ek[(p0 + m) * DA + kt + sk4]);
                sB[(sk4 + 0) * LDP + m] = ee.x; sB[(sk4 + 1) * LDP + m] = ee.y;
                sB[(sk4 + 2) * LDP + m] = ee.z; sB[(sk4 + 3) * LDP + m] = ee.w;
            }
            __syncthreads();
            #pragma unroll
            for (int kk = 0; kk < 32; ++kk) {
                float a0 = sA[kk * LDP + ty * 2 + 0];
                float a1 = sA[kk * LDP + ty * 2 + 1];
                float4 b4 = *reinterpret_cast<const float4*>(&sB[kk * LDP + tx4]);
                FMA8(a0, a1, b4, acc)
            }
            __syncthreads();
        }
        #pragma unroll
        for (int i = 0; i < 2; ++i) {
            float4 o = make_float4(acc[i][0], acc[i][1], acc[i][2], acc[i][3]);
            *reinterpret_cast<float4*>(&Gm[(e0 + ty * 2 + i) * P + p0 + tx4]) = o;
        }
    } else if (bi == 384) {
        // ---- vec4[j][f] = sum_e Uq[e,f] * (sum_d Vk[e,d]*w4[j][d])
        float* w4  = sA;   // [4][256]
        float* tmp = sB;   // [256][4]
        float gkd = gk[tid];
        w4[0 * 256 + tid] = wk[tid] * gkd;
        w4[1 * 256 + tid] = bk[tid] * gkd;
        w4[2 * 256 + tid] = gkd;
        w4[3 * 256 + tid] = bkln[tid];
        __syncthreads();
        const int dl = tid & 15, eg = tid >> 4;
        for (int eb = 0; eb < 16; ++eb) {
            int e = eb * 16 + eg;
            float p0 = 0.f, p1 = 0.f, p2 = 0.f, p3 = 0.f;
            #pragma unroll
            for (int t = 0; t < 16; ++t) {
                int d = dl + t * 16;
                float v = Vk[e * DA + d];
                p0 = fmaf(v, w4[d], p0);
                p1 = fmaf(v, w4[256 + d], p1);
                p2 = fmaf(v, w4[512 + d], p2);
                p3 = fmaf(v, w4[768 + d], p3);
            }
            #pragma unroll
            for (int m = 8; m > 0; m >>= 1) {
                p0 += __shfl_xor(p0, m, 16);
                p1 += __shfl_xor(p1, m, 16);
                p2 += __shfl_xor(p2, m, 16);
                p3 += __shfl_xor(p3, m, 16);
            }
            if (dl == 0) {
                tmp[e * 4 + 0] = p0; tmp[e * 4 + 1] = p1;
                tmp[e * 4 + 2] = p2; tmp[e * 4 + 3] = p3;
            }
        }
        __syncthreads();
        float a0 = 0.f, a1 = 0.f, a2 = 0.f, a3 = 0.f;
        for (int e = 0; e < 256; ++e) {
            float u = Uq[e * DA + tid];
            a0 = fmaf(u, tmp[e * 4 + 0], a0);
            a1 = fmaf(u, tmp[e * 4 + 1], a1);
            a2 = fmaf(u, tmp[e * 4 + 2], a2);
            a3 = fmaf(u, tmp[e * 4 + 3], a3);
        }
        vec4[tid] = a0; vec4[256 + tid] = a1; vec4[512 + tid] = a2; vec4[768 + tid] = a3;
    } else {
        // ---- kp: per-p LN stats
        const int p = bi - 385, d = tid;
        const float inv = 1.0f / DA;
        float ek = Ek[p * DA + d], ev = Ev[p * DA + d];
        float wkd = wk[d], wvd = wv[d];
        float ck = bk[d] + ek, cv = bv[d] + ev;

        float Sck  = block_reduce_sum(ck, red);
        float Sck2 = block_reduce_sum(ck * ck, red);
        float Swck = block_reduce_sum(wkd * ck, red);
        float Scv  = block_reduce_sum(cv, red);
        float Scv2 = block_reduce_sum(cv * cv, red);
        float Swcv = block_reduce_sum(wvd * cv, red);
        float Swk  = block_reduce_sum(wkd, red);
        float Swv  = block_reduce_sum(wvd, red);

        float mwk = Swk * inv, mwv = Swv * inv;
        float mck = Sck * inv, mcv = Scv * inv;
        if (d == 0) {
            pst[0 * P + p] = mck;
            pst[1 * P + p] = Swck * inv - mwk * mck;  // Bk
            pst[2 * P + p] = Sck2 * inv - mck * mck;  // Ck
            pst[3 * P + p] = mcv;
            pst[4 * P + p] = Swcv * inv - mwv * mcv;  // Bv
            pst[5 * P + p] = Scv2 * inv - mcv * mcv;  // Cv
        }
        if (p == 0) {
            float Swk2 = block_reduce_sum(wkd * wkd, red);
            float Swv2 = block_reduce_sum(wvd * wvd, red);
            if (d == 0) {
                scal4[0] = mwk;
                scal4[1] = Swk2 * inv - mwk * mwk;   // A_k
                scal4[2] = mwv;
                scal4[3] = Swv2 * inv - mwv * mwv;   // A_v
            }
        }
    }
}

// ---------------------------------------------------------------- KC:
//  bi in [0,512)   : LN(sum qp + bq) -> q; 4 scalar dots vs vec4 -> bscal
//  bi in [512,640) : N[f][p] = sum_e Uq[e,f]*G[e,p]  (both operands natural [k][out])
__global__ __launch_bounds__(256) void KC(const float* __restrict__ qp, const float* __restrict__ bq,
                                          const float* __restrict__ gq, const float* __restrict__ bqln,
                                          const float* __restrict__ vec4, const float* __restrict__ Uq,
                                          const float* __restrict__ Gm,
                                          float* __restrict__ qout, float* __restrict__ Nm,
                                          float* __restrict__ bscal) {
    __shared__ __align__(16) float sA[32 * LDP];
    __shared__ __align__(16) float sB[32 * LDP];
    __shared__ float red[4];
    const int tid = threadIdx.x;
    const int bi = blockIdx.x;

    if (bi < 512) {
        const int b = bi, d = tid;
        float x = bq[d];
        #pragma unroll
        for (int ks = 0; ks < 8; ++ks) x += qp[ks * (B * DA) + b * DA + d];
        float mu = block_reduce_sum(x, red) * (1.0f / DA);
        float xc = x - mu;
        float var = block_reduce_sum(xc * xc, red) * (1.0f / DA);
        float qv = xc * rsqrtf(var + 1e-5f) * gq[d] + bqln[d];
        qout[b * DA + d] = qv;
        float Wg = block_reduce_sum(qv * vec4[d], red);
        float Cg = block_reduce_sum(qv * vec4[256 + d], red);
        float G_ = block_reduce_sum(qv * vec4[512 + d], red);
        float Bb = block_reduce_sum(qv * vec4[768 + d], red);
        if (d == 0) {
            bscal[b] = Wg; bscal[B + b] = Cg; bscal[2 * B + b] = G_; bscal[3 * B + b] = Bb;
        }
    } else {
        const int b2 = bi - 512;
        const int f0 = (b2 & 7) * 32, p0 = (b2 >> 3) * 64;
        const int sm = tid >> 3, sk4 = (tid & 7) * 4;
        const int kr = tid >> 4, n4 = (tid & 15) * 4;
        const int ty = tid >> 4, tx4 = (tid & 15) * 4;
        float acc[2][4] = {};
        for (int kt = 0; kt < 256; kt += 32) {
            *reinterpret_cast<float4*>(&sA[sm * LDP + sk4]) =
                *reinterpret_cast<const float4*>(&Uq[(kt + sm) * DA + f0 + sk4]);
            #pragma unroll
            for (int pass = 0; pass < 2; ++pass) {
                int k = kr + pass * 16;
                *reinterpret_cast<float4*>(&sB[k * LDP + n4]) =
                    *reinterpret_cast<const float4*>(&Gm[(kt + k) * P + p0 + n4]);
            }
            __syncthreads();
            #pragma unroll
            for (int kk = 0; kk < 32; ++kk) {
                float a0 = sA[kk * LDP + ty * 2 + 0];
                float a1 = sA[kk * LDP + ty * 2 + 1];
                float4 b4 = *reinterpret_cast<const float4*>(&sB[kk * LDP + tx4]);
                FMA8(a0, a1, b4, acc)
            }
            __syncthreads();
        }
        #pragma unroll
        for (int i = 0; i < 2; ++i) {
            float4 o = make_float4(acc[i][0], acc[i][1], acc[i][2], acc[i][3]);
            *reinterpret_cast<float4*>(&Nm[(f0 + ty * 2 + i) * P + p0 + tx4]) = o;
        }
    }
}

// ---------------------------------------------------------------- KD: e = q @ N (K=256) + fused epilogue -> u (out_alpha), w = u*rstd_v
__global__ __launch_bounds__(256) void KD(const float* __restrict__ q, const float* __restrict__ Nm,
                                          const float* __restrict__ desc, const float* __restrict__ bscal,
                                          const float* __restrict__ pst, const float* __restrict__ scal4,
                                          float* __restrict__ u_out, float* __restrict__ w) {
    __shared__ __align__(16) float sA[32 * LDP];
    __shared__ __align__(16) float sB[32 * LDP];
    const int tid = threadIdx.x, bi = blockIdx.x;
    const int b0 = (bi & 15) * 32, p0 = (bi >> 4) * 64;
    const int sm = tid >> 3, sk4 = (tid & 7) * 4;
    const int kr = tid >> 4, n4 = (tid & 15) * 4;
    const int ty = tid >> 4, tx4 = (tid & 15) * 4;
    float acc[2][4] = {};
    for (int kt = 0; kt < 256; kt += 32) {
        float4 qv4 = *reinterpret_cast<const float4*>(&q[(b0 + sm) * DA + kt + sk4]);
        sA[(sk4 + 0) * LDP + sm] = qv4.x; sA[(sk4 + 1) * LDP + sm] = qv4.y;
        sA[(sk4 + 2) * LDP + sm] = qv4.z; sA[(sk4 + 3) * LDP + sm] = qv4.w;
        #pragma unroll
        for (int pass = 0; pass < 2; ++pass) {
            int k = kr + pass * 16;
            *reinterpret_cast<float4*>(&sB[k * LDP + n4]) =
                *reinterpret_cast<const float4*>(&Nm[(kt + k) * P + p0 + n4]);
        }
        __syncthreads();
        #pragma unroll
        for (int kk = 0; kk < 32; ++kk) {
            float a0 = sA[kk * LDP + ty * 2 + 0];
            float a1 = sA[kk * LDP + ty * 2 + 1];
            float4 b4 = *reinterpret_cast<const float4*>(&sB[kk * LDP + tx4]);
            FMA8(a0, a1, b4, acc)
        }
        __syncthreads();
    }
    const float mwk = scal4[0], Ak = scal4[1], Av = scal4[3];
    #pragma unroll
    for (int i = 0; i < 2; ++i) {
        int b = b0 + ty * 2 + i;
        float Wg = bscal[b], Cg = bscal[B + b], G_ = bscal[2 * B + b], Bb = bscal[3 * B + b];
        float4 uo, wo;
        float* up = &uo.x; float* wp = &wo.x;
        #pragma unroll
        for (int j = 0; j < 4; ++j) {
            int p = p0 + tx4 + j;
            float s = desc[b * P + p];
            float mck = pst[p], Bk = pst[P + p], Ck = pst[2 * P + p];
            float var = fmaf(s, fmaf(s, Ak, 2.0f * Bk), Ck);
            float rstd = rsqrtf(var + 1e-5f);
            float mu = fmaf(s, mwk, mck);
            float e = (rstd * (fmaf(s, Wg, Cg) + acc[i][j] - mu * G_) + Bb) * 0.0625f;
            float uu = 1.0f / (1.0f + expf(-e));
            float Bv = pst[4 * P + p], Cv = pst[5 * P + p];
            float varv = fmaf(s, fmaf(s, Av, 2.0f * Bv), Cv);
            float rv = rsqrtf(varv + 1e-5f);
            up[j] = uu; wp[j] = uu * rv;
        }
        *reinterpret_cast<float4*>(&u_out[b * P + p0 + tx4]) = uo;
        *reinterpret_cast<float4*>(&w[b * P + p0 + tx4]) = wo;
    }
}

// ---------------------------------------------------------------- KF: cpart[ks] = w @ Ev partial (64x64 tile, K-chunk 64, KS=16)
__global__ __launch_bounds__(256) void KF(const float* __restrict__ w, const float* __restrict__ Ev,
                                          float* __restrict__ cpart) {
    __shared__ __align__(16) float sA[32 * LDP];
    __shared__ __align__(16) float sB[32 * LDP];
    const int tid = threadIdx.x, bi = blockIdx.x;
    const int mt = bi & 7, nt = (bi >> 3) & 3, ks = bi >> 5;
    const int b0 = mt * 64, d0 = nt * 64, kc = ks * 64;
    const int sm = tid >> 3, sk4 = (tid & 7) * 4;
    const int kr = tid >> 4, n4 = (tid & 15) * 4;
    const int ty4 = (tid >> 4) * 4, tx4 = (tid & 15) * 4;
    float acc[4][4] = {};
    for (int kt = 0; kt < 64; kt += 32) {
        const int kg = kc + kt;
        #pragma unroll
        for (int pass = 0; pass < 2; ++pass) {
            int m = sm + pass * 32;
            float4 av = *reinterpret_cast<const float4*>(&w[(b0 + m) * P + kg + sk4]);
            sA[(sk4 + 0) * LDP + m] = av.x; sA[(sk4 + 1) * LDP + m] = av.y;
            sA[(sk4 + 2) * LDP + m] = av.z; sA[(sk4 + 3) * LDP + m] = av.w;
            int k = kr + pass * 16;
            *reinterpret_cast<float4*>(&sB[k * LDP + n4]) =
                *reinterpret_cast<const float4*>(&Ev[(kg + k) * DA + d0 + n4]);
        }
        __syncthreads();
        #pragma unroll
        for (int kk = 0; kk < 32; ++kk) {
            float4 a4 = *reinterpret_cast<const float4*>(&sA[kk * LDP + ty4]);
            float4 b4 = *reinterpret_cast<const float4*>(&sB[kk * LDP + tx4]);
            FMA16(a4, b4, acc)
        }
        __syncthreads();
    }
    float* outp = cpart + ks * (B * DA);
    #pragma unroll
    for (int i = 0; i < 4; ++i) {
        float4 o = make_float4(acc[i][0], acc[i][1], acc[i][2], acc[i][3]);
        *reinterpret_cast<float4*>(&outp[(b0 + ty4 + i) * DA + d0 + tx4]) = o;
    }
}

// ---------------------------------------------------------------- KG: per-b scalars from u/w, alpha = u/S (in place), final c
__global__ __launch_bounds__(256) void KG(const float* __restrict__ desc, const float* __restrict__ pst,
                                          const float* __restrict__ scal4, const float* __restrict__ cpart,
                                          const float* __restrict__ gv, const float* __restrict__ wv,
                                          const float* __restrict__ bvv, const float* __restrict__ bvln,
                                          float* __restrict__ alpha_io, const float* __restrict__ wbuf,
                                          float* __restrict__ out_c) {
    __shared__ float red[4];
    const int b = blockIdx.x, tid = threadIdx.x;
    const float mwv = scal4[2];
    float u[4], wl[4], sv[4], mv[4];
    #pragma unroll
    for (int j = 0; j < 4; ++j) {
        int p = j * 256 + tid;
        u[j]  = alpha_io[b * P + p];
        wl[j] = wbuf[b * P + p];
        sv[j] = desc[b * P + p];
        mv[j] = fmaf(sv[j], mwv, pst[3 * P + p]);
    }
    float S   = block_reduce_sum(u[0] + u[1] + u[2] + u[3], red);
    float SB  = block_reduce_sum(wl[0] + wl[1] + wl[2] + wl[3], red);
    float SBs = block_reduce_sum(wl[0]*sv[0] + wl[1]*sv[1] + wl[2]*sv[2] + wl[3]*sv[3], red);
    float SBm = block_reduce_sum(wl[0]*mv[0] + wl[1]*mv[1] + wl[2]*mv[2] + wl[3]*mv[3], red);
    float invS = 1.0f / (S + 1e-12f);
    float T = S * invS;
    #pragma unroll
    for (int j = 0; j < 4; ++j)
        alpha_io[b * P + j * 256 + tid] = u[j] * invS;
    const int d = tid;
    float csum = 0.f;
    #pragma unroll
    for (int ks = 0; ks < 16; ++ks) csum += cpart[ks * (B * DA) + b * DA + d];
    out_c[b * DA + d] = invS * (gv[d] * (wv[d] * SBs + bvv[d] * SB + csum - SBm)) + bvln[d] * T;
}

// ---------------------------------------------------------------- launch
extern "C" void kernel_launch(void* const* d_in, const int* in_sizes, int n_in,
                              void* d_out, int out_size, void* d_ws, size_t ws_size,
                              hipStream_t stream) {
    (void)in_sizes; (void)n_in; (void)out_size; (void)ws_size;
    const float* hg   = (const float*)d_in[0];
    const float* desc = (const float*)d_in[1];
    const float* Wq   = (const float*)d_in[2];
    const float* bq   = (const float*)d_in[3];
    const float* wk   = (const float*)d_in[4];
    const float* bk   = (const float*)d_in[5];
    const float* wv   = (const float*)d_in[6];
    const float* bv   = (const float*)d_in[7];
    const float* Ek   = (const float*)d_in[8];
    const float* Ev   = (const float*)d_in[9];
    const float* Uq   = (const float*)d_in[10];
    const float* Vk   = (const float*)d_in[11];
    const float* gq   = (const float*)d_in[12];
    const float* bqln = (const float*)d_in[13];
    const float* gk   = (const float*)d_in[14];
    const float* bkln = (const float*)d_in[15];
    const float* gv   = (const float*)d_in[16];
    const float* bvln = (const float*)d_in[17];

    float* out = (float*)d_out;
    float* out_c = out;              // B*DA
    float* out_alpha = out + B * DA; // B*P (u written by KD, normalized in place by KG)

    // ws layout (floats), total ~16.6 MB of the 256 MiB workspace — no aliasing.
    float* ws = (float*)d_ws;
    float* qp    = ws;                 // 1048576
    float* Gm    = ws + 1048576;       // 262144
    float* Nm    = ws + 1310720;       // 262144
    float* q     = ws + 1572864;       // 131072
    float* w     = ws + 1703936;       // 524288
    float* cpart = ws + 2228224;       // 2097152
    float* vec4  = ws + 4325376;       // 1024
    float* bscal = ws + 4326400;       // 2048
    float* pst   = ws + 4328448;       // 6144
    float* scal4 = ws + 4334592;       // 4

    KA<<<1409, 256, 0, stream>>>(hg, Wq, Uq, Vk, Ek, Ev, wk, bk, wv, bv, gk, bkln,
                                 qp, Gm, pst, scal4, vec4);
    KC<<<640, 256, 0, stream>>>(qp, bq, gq, bqln, vec4, Uq, Gm, q, Nm, bscal);
    KD<<<256, 256, 0, stream>>>(q, Nm, desc, bscal, pst, scal4, out_alpha, w);
    KF<<<512, 256, 0, stream>>>(w, Ev, cpart);
    KG<<<512, 256, 0, stream>>>(desc, pst, scal4, cpart, gv, wv, bv, bvln, out_alpha, w, out_c);
}